// Round 7
// baseline (3696.943 us; speedup 1.0000x reference)
//
#include <hip/hip_runtime.h>
#include <stdint.h>

#define Bn 128
#define Tn 256
#define En 300
#define EPn 320          // E padded to multiple of 16 (MFMA K)
#define Hn 1024
#define PADIDX 1
#define NBLK 256         // 2 groups x 128 col-blocks
#define NROT 16          // h buffer rotation depth (fresh address per step)

typedef short s16x8 __attribute__((ext_vector_type(8)));
typedef float f32x16 __attribute__((ext_vector_type(16)));
typedef unsigned int u32;
typedef u32 u32x4 __attribute__((ext_vector_type(4)));

#define LDQ32(p) __hip_atomic_load((p), __ATOMIC_RELAXED, __HIP_MEMORY_SCOPE_SYSTEM)
#define ST32(p, v) __hip_atomic_store((p), (v), __ATOMIC_RELAXED, __HIP_MEMORY_SCOPE_SYSTEM)

__device__ __forceinline__ unsigned short f2bf(float f) {
  u32 u = __builtin_bit_cast(u32, f);
  u32 r = (u + 0x7fffu + ((u >> 16) & 1u)) >> 16;  // RNE
  return (unsigned short)r;
}
__device__ __forceinline__ float bf2f(unsigned short h) {
  u32 u = ((u32)h) << 16;
  return __builtin_bit_cast(float, u);
}
__device__ __forceinline__ float sigmoidf_(float x) { return 1.f / (1.f + __expf(-x)); }
__device__ __forceinline__ float tanhf_(float x) { return 1.f - 2.f / (__expf(2.f * x) + 1.f); }

// h load: sc0 only -> bypass L1, cache in XCD L2 (co-XCD amortization). Result
// NOT valid until manual s_waitcnt.
__device__ __forceinline__ u32x4 ldg_sc0_x4(const u32* p) {
  u32x4 r;
  asm volatile("global_load_dwordx4 %0, %1, off sc0" : "=v"(r) : "v"(p));
  return r;
}
#define WAITV16 do { asm volatile("s_waitcnt vmcnt(16)" ::: "memory"); \
                     __builtin_amdgcn_sched_barrier(0); } while (0)
#define WAITV8  do { asm volatile("s_waitcnt vmcnt(8)" ::: "memory");  \
                     __builtin_amdgcn_sched_barrier(0); } while (0)
#define WAITV0  do { asm volatile("s_waitcnt vmcnt(0)" ::: "memory");  \
                     __builtin_amdgcn_sched_barrier(0); } while (0)

// ---------------- K0: lengths -> tstar / padflag ----------------
__global__ void prep_kernel(const int* __restrict__ x, int* __restrict__ tstar,
                            int* __restrict__ padflag) {
  int b = threadIdx.x;
  if (b < Bn) {
    int len = 0;
    for (int t = 0; t < Tn; ++t) len += (x[b * Tn + t] != PADIDX) ? 1 : 0;
    int ts = (len > 0) ? (len - 1) : (Tn - 1);  // jax wraps index -1
    tstar[b] = ts;
    padflag[b] = (x[b * Tn + ts] == PADIDX) ? 1 : 0;
  }
}

// ---------------- K1: inp[t][b][k] = bf16(embed[x[b,t]][k]), k>=300 -> 0 ----
__global__ void gather_kernel(const int* __restrict__ x, const float* __restrict__ embed,
                              unsigned short* __restrict__ inp) {
  int idx = blockIdx.x * 256 + threadIdx.x;   // total = Tn*Bn*EPn
  int k = idx % EPn;
  int rem = idx / EPn;          // t*Bn + b
  int b = rem & (Bn - 1);
  int t = rem >> 7;
  int tok = x[b * Tn + t];
  float v = (k < En) ? embed[(size_t)tok * En + k] : 0.f;
  inp[idx] = f2bf(v);
}

// ---------------- K1b: W_ih -> bf16, K padded to 320 ----------------
__global__ void wihcvt_kernel(const float* __restrict__ Wih, unsigned short* __restrict__ wih_bf) {
  int idx = blockIdx.x * 256 + threadIdx.x;   // total = 4096*EPn
  int k = idx % EPn;
  int g = idx / EPn;
  float v = (k < En) ? Wih[(size_t)g * En + k] : 0.f;
  wih_bf[idx] = f2bf(v);
}

// ---------------- K2: persistent LSTM scan (32x32x16 MFMA) ----------------
// 256 blocks x 128 thr (2 waves). group = bid>>7 (64 batches); 128 col-blocks/group,
// each 8 hidden units (32 gate cols = N tile). Wave = 32 batches x 32 cols, K=1024.
// W_hh hi/lo in LDS, KK-MAJOR CONTIGUOUS layout: wave ds_read_b128 spans 1024
// contiguous bytes -> zero bank conflicts. h: packed u32 (bf16 hi | lo<<16),
// 16-buffer rotation; stores sc0sc1 (write-through L3), loads sc0 (L2-fill);
// acquire-fence every 8 steps kills stale lines before address reuse at t+16.
// Sync: per-block monotone flag; both waves poll 128 flags (2 loads + ballot).
__global__ __launch_bounds__(128, 1) void lstm_scan(
    const float* __restrict__ Whh, const unsigned short* __restrict__ wih_bf,
    const float* __restrict__ bih, const float* __restrict__ bhh,
    const unsigned short* __restrict__ inp, const int* __restrict__ tstar,
    const int* __restrict__ padflag, u32* __restrict__ h_pk,
    float* __restrict__ hsel, u32* __restrict__ flags) {
  __shared__ unsigned short lds_hi[32768];   // 64 KB: [m=kk*2+half][n][j]
  __shared__ unsigned short lds_lo[32768];   // 64 KB

  const int bid = blockIdx.x;
  const int group = bid >> 7;              // 0: batches 0-63, 1: batches 64-127
  const int cb = bid & 127;                // col-block within group
  const int u0 = cb * 8;                   // 8 hidden units per block
  const int tid = threadIdx.x;

  // --- W_hh slice -> LDS hi/lo, kk-major: elem i = m*256 + nn*8 + j ---
  for (int i = tid; i < 32768; i += 128) {
    int m = i >> 8, rem = i & 255;
    int nn = rem >> 3, j = rem & 7;
    int k = (m >> 1) * 16 + (m & 1) * 8 + j;
    int grow = (nn >> 3) * Hn + u0 + (nn & 7);
    float w = Whh[(size_t)grow * Hn + k];
    unsigned short hi = f2bf(w);
    lds_hi[i] = hi;
    lds_lo[i] = f2bf(w - bf2f(hi));
  }
  __syncthreads();

  const int wv = tid >> 6, l = tid & 63;
  const int n = l & 31;                     // B col / A row-within-tile / C col
  const int h5 = l >> 5;                    // k-half selector
  const int gate = n >> 3;                  // col n -> (gate, unit=n&7)
  const int bA = group * 64 + wv * 32;      // wave's batch base
  const int gcol = gate * Hn + u0 + (n & 7);
  const float bias = bih[gcol] + bhh[gcol];
  const u32 lbase = (u32)(h5 * 512 + n * 16);  // LDS byte base (contig per wave)
  u32* const fg = flags + (group << 7);     // group's 128 per-block flags

  // tstar/padflag packed for the lane's 16 C-rows: row(r) = (r&3)+8*(r>>2)+4*h5
  u32 tsp[4] = {0u, 0u, 0u, 0u}, pfm = 0u;
#pragma unroll
  for (int r = 0; r < 16; ++r) {
    int b = bA + (r & 3) + 8 * (r >> 2) + 4 * h5;
    tsp[r >> 2] |= ((u32)tstar[b] & 255u) << ((r & 3) * 8);
    pfm |= ((u32)padflag[b] & 1u) << r;
  }
  float creg[16];
#pragma unroll
  for (int r = 0; r < 16; ++r) creg[r] = 0.f;

  const char* base_hi = (const char*)lds_hi;
  const char* base_lo = (const char*)lds_lo;

  u32x4 qa[3][4][2];  // h prefetch: 3 chunks x 4 kk x 32B

#define ISSUE_A(BUF, C)                                                          \
  _Pragma("unroll") for (int ii = 0; ii < 4; ++ii) {                             \
    const u32* p = hbase + ((C) * 4 + ii) * 16;                                  \
    qa[BUF][ii][0] = ldg_sc0_x4(p);                                              \
    qa[BUF][ii][1] = ldg_sc0_x4(p + 4);                                          \
  }
#define BODY_(BUF, C)                                                            \
  _Pragma("unroll") for (int ii = 0; ii < 4; ++ii) {                             \
    int kk = (C) * 4 + ii;                                                       \
    u32x4 q0 = qa[BUF][ii][0], q1 = qa[BUF][ii][1];                              \
    u32x4 vh, vl;                                                                \
    vh[0] = __builtin_amdgcn_perm(q0[1], q0[0], 0x05040100u);                    \
    vh[1] = __builtin_amdgcn_perm(q0[3], q0[2], 0x05040100u);                    \
    vh[2] = __builtin_amdgcn_perm(q1[1], q1[0], 0x05040100u);                    \
    vh[3] = __builtin_amdgcn_perm(q1[3], q1[2], 0x05040100u);                    \
    vl[0] = __builtin_amdgcn_perm(q0[1], q0[0], 0x07060302u);                    \
    vl[1] = __builtin_amdgcn_perm(q0[3], q0[2], 0x07060302u);                    \
    vl[2] = __builtin_amdgcn_perm(q1[1], q1[0], 0x07060302u);                    \
    vl[3] = __builtin_amdgcn_perm(q1[3], q1[2], 0x07060302u);                    \
    s16x8 ahi = __builtin_bit_cast(s16x8, vh);                                   \
    s16x8 alo = __builtin_bit_cast(s16x8, vl);                                   \
    s16x8 bh = *(const s16x8*)(base_hi + (u32)kk * 1024 + lbase);                \
    s16x8 bl = *(const s16x8*)(base_lo + (u32)kk * 1024 + lbase);                \
    acc = __builtin_amdgcn_mfma_f32_32x32x16_bf16(ahi, bh, acc, 0, 0, 0);        \
    acc = __builtin_amdgcn_mfma_f32_32x32x16_bf16(alo, bh, acc, 0, 0, 0);        \
    acc = __builtin_amdgcn_mfma_f32_32x32x16_bf16(ahi, bl, acc, 0, 0, 0);        \
  }

  for (int t = 0; t < Tn; ++t) {
    f32x16 acc;
#pragma unroll
    for (int r = 0; r < 16; ++r) acc[r] = bias;

    // ---- x-projection FIRST (h-independent): overlaps the flag wait ----
    const unsigned short* ip = inp + ((size_t)t * Bn + bA + n) * EPn + h5 * 8;
    const unsigned short* wp = wih_bf + (size_t)gcol * EPn + h5 * 8;
#pragma unroll
    for (int ks = 0; ks < EPn / 16; ++ks) {
      s16x8 a = *(const s16x8*)(ip + ks * 16);
      s16x8 bfr = *(const s16x8*)(wp + ks * 16);
      acc = __builtin_amdgcn_mfma_f32_32x32x16_bf16(a, bfr, acc, 0, 0, 0);
    }

    // ---- wait for all 128 blocks of my group to have published h(t) ----
    if (t) {
      u32 spins = 0;
      for (;;) {
        u32 f0 = LDQ32(fg + l);
        u32 f1 = LDQ32(fg + 64 + l);
        if (__ballot((f0 >= (u32)t) & (f1 >= (u32)t)) == ~0ull) break;
        __builtin_amdgcn_s_sleep(2);
        if (++spins > 400000u) break;  // watchdog: dead unless deadlock
      }
    }
    WAITV0;  // clean vmcnt before counted prefetch chain

    // ---- recurrent K=1024: 16 chunks x 4 kk, 3-deep prefetch, counted vmcnt ----
    const u32* hbase = h_pk + (size_t)(t & (NROT - 1)) * (Bn * Hn) +
                       (size_t)(bA + n) * Hn + h5 * 8;
    ISSUE_A(0, 0) ISSUE_A(1, 1) ISSUE_A(2, 2)
    WAITV16; BODY_(0, 0) ISSUE_A(0, 3)
    WAITV16; BODY_(1, 1) ISSUE_A(1, 4)
    WAITV16; BODY_(2, 2) ISSUE_A(2, 5)
    WAITV16; BODY_(0, 3) ISSUE_A(0, 6)
    WAITV16; BODY_(1, 4) ISSUE_A(1, 7)
    WAITV16; BODY_(2, 5) ISSUE_A(2, 8)
    WAITV16; BODY_(0, 6) ISSUE_A(0, 9)
    WAITV16; BODY_(1, 7) ISSUE_A(1, 10)
    WAITV16; BODY_(2, 8) ISSUE_A(2, 11)
    WAITV16; BODY_(0, 9) ISSUE_A(0, 12)
    WAITV16; BODY_(1, 10) ISSUE_A(1, 13)
    WAITV16; BODY_(2, 11) ISSUE_A(2, 14)
    WAITV16; BODY_(0, 12) ISSUE_A(0, 15)
    WAITV16; BODY_(1, 13)
    WAITV8;  BODY_(2, 14)
    WAITV0;  BODY_(0, 15)

    // ---- gates (shfl mix over col bits 3..4) + state update ----
    u32* const hout = h_pk + (size_t)((t + 1) & (NROT - 1)) * (Bn * Hn);
#pragma unroll
    for (int r = 0; r < 16; ++r) {
      float pre = acc[r];
      float v = (gate == 2) ? tanhf_(pre) : sigmoidf_(pre);
      float vB = __shfl_xor(v, 8);
      float vC = __shfl_xor(v, 16);
      float vD = __shfl_xor(vB, 16);
      float i_ = (gate & 2) ? ((gate & 1) ? vD : vC) : ((gate & 1) ? vB : v);
      float f_ = (gate & 2) ? ((gate & 1) ? vC : vD) : ((gate & 1) ? v : vB);
      float g_ = (gate & 2) ? ((gate & 1) ? vB : v) : ((gate & 1) ? vD : vC);
      float o_ = (gate & 2) ? ((gate & 1) ? v : vB) : ((gate & 1) ? vC : vD);
      float cn = f_ * creg[r] + i_ * g_;
      creg[r] = cn;
      float h = o_ * tanhf_(cn);
      if (gate == 0) {
        int b = bA + (r & 3) + 8 * (r >> 2) + 4 * h5;
        unsigned short hh = f2bf(h);
        unsigned short hl = f2bf(h - bf2f(hh));
        ST32(hout + (size_t)b * Hn + u0 + n, (u32)hh | ((u32)hl << 16));
        u32 tsb = (tsp[r >> 2] >> ((r & 3) * 8)) & 255u;
        if ((u32)t == tsb)
          hsel[(size_t)b * Hn + u0 + n] = ((pfm >> r) & 1u) ? 0.f : h;
      }
    }

    // ---- arrival: block barrier drains both waves' vmcnt, then publish flag ----
    __syncthreads();
    if (tid == 0) ST32(fg + cb, (u32)(t + 1));
    // every 8 steps: invalidate local L2/L1 h copies (amortized); guarantees no
    // stale line survives to the address's reuse at t+16
    if ((t & 7) == 7) __builtin_amdgcn_fence(__ATOMIC_ACQUIRE, "agent");
  }
#undef ISSUE_A
#undef BODY_
}

// ---------------- K3: out[b][o] = hsel[b]·W_out[o] + b_out[o] ----------------
__global__ void head_kernel(const float* __restrict__ hsel, const float* __restrict__ Wout,
                            const float* __restrict__ bout, float* __restrict__ out) {
  int b = blockIdx.x;
  int l = threadIdx.x;  // 64 threads
  float s0 = 0.f, s1 = 0.f, s2 = 0.f;
  for (int j = l; j < Hn; j += 64) {
    float h = hsel[(size_t)b * Hn + j];
    s0 += h * Wout[j];
    s1 += h * Wout[Hn + j];
    s2 += h * Wout[2 * Hn + j];
  }
#pragma unroll
  for (int m = 32; m; m >>= 1) {
    s0 += __shfl_xor(s0, m);
    s1 += __shfl_xor(s1, m);
    s2 += __shfl_xor(s2, m);
  }
  if (l == 0) {
    out[b * 3 + 0] = s0 + bout[0];
    out[b * 3 + 1] = s1 + bout[1];
    out[b * 3 + 2] = s2 + bout[2];
  }
}

extern "C" void kernel_launch(void* const* d_in, const int* in_sizes, int n_in,
                              void* d_out, int out_size, void* d_ws, size_t ws_size,
                              hipStream_t stream) {
  const int* x = (const int*)d_in[0];
  const float* embed = (const float*)d_in[1];
  const float* Wih = (const float*)d_in[2];
  const float* Whh = (const float*)d_in[3];
  const float* bih = (const float*)d_in[4];
  const float* bhh = (const float*)d_in[5];
  const float* Wout = (const float*)d_in[6];
  const float* bout = (const float*)d_in[7];
  float* out = (float*)d_out;

  // ws layout
  const size_t INP_BYTES = (size_t)Tn * Bn * EPn * 2;        // 20,971,520
  const size_t WIH_BYTES = (size_t)4 * Hn * EPn * 2;         //  2,621,440
  const size_t HPK_BYTES = (size_t)NROT * Bn * Hn * 4;       //  8,388,608
  const size_t HSEL_BYTES = (size_t)Bn * Hn * 4;             //    524,288
  char* p = (char*)d_ws;
  unsigned short* inp = (unsigned short*)p;             p += INP_BYTES;
  unsigned short* wih_bf = (unsigned short*)p;          p += WIH_BYTES;
  u32* h_pk = (u32*)p;                                  p += HPK_BYTES;
  float* hsel = (float*)p;                              p += HSEL_BYTES;
  int* tstar = (int*)p;                                 p += 512;
  int* padflag = (int*)p;                               p += 512;
  u32* flags = (u32*)p;                                 p += 1024;

  // per-launch init: h(0) = 0 (rotation slot 0), flags = 0 (self-contained replay)
  hipMemsetAsync(h_pk, 0, (size_t)Bn * Hn * 4, stream);
  hipMemsetAsync(flags, 0, 1024, stream);

  prep_kernel<<<1, 128, 0, stream>>>(x, tstar, padflag);
  gather_kernel<<<(Tn * Bn * EPn) / 256, 256, 0, stream>>>(x, embed, inp);
  wihcvt_kernel<<<(4 * Hn * EPn) / 256, 256, 0, stream>>>(Wih, wih_bf);
  lstm_scan<<<NBLK, 128, 0, stream>>>(Whh, wih_bf, bih, bhh, inp, tstar, padflag,
                                      h_pk, hsel, flags);
  head_kernel<<<Bn, 64, 0, stream>>>(hsel, Wout, bout, out);
}

// Round 8
// 3126.208 us; speedup vs baseline: 1.1826x; 1.1826x over previous
//
#include <hip/hip_runtime.h>
#include <stdint.h>

#define Bn 128
#define Tn 256
#define En 300
#define EPn 320          // E padded to multiple of 32 (MFMA K)
#define Hn 1024
#define PADIDX 1
#define NBLK 256         // 2 groups x 128 col-blocks
#define NROT 16          // h buffer rotation depth (fresh address per step)

typedef short s16x8 __attribute__((ext_vector_type(8)));
typedef float f32x4 __attribute__((ext_vector_type(4)));
typedef unsigned int u32;
typedef u32 u32x4 __attribute__((ext_vector_type(4)));

#define LDQ32(p) __hip_atomic_load((p), __ATOMIC_RELAXED, __HIP_MEMORY_SCOPE_SYSTEM)
#define ST32(p, v) __hip_atomic_store((p), (v), __ATOMIC_RELAXED, __HIP_MEMORY_SCOPE_SYSTEM)

__device__ __forceinline__ unsigned short f2bf(float f) {
  u32 u = __builtin_bit_cast(u32, f);
  u32 r = (u + 0x7fffu + ((u >> 16) & 1u)) >> 16;  // RNE
  return (unsigned short)r;
}
__device__ __forceinline__ float bf2f(unsigned short h) {
  u32 u = ((u32)h) << 16;
  return __builtin_bit_cast(float, u);
}
__device__ __forceinline__ float sigmoidf_(float x) { return 1.f / (1.f + __expf(-x)); }
__device__ __forceinline__ float tanhf_(float x) { return 1.f - 2.f / (__expf(2.f * x) + 1.f); }

// h load: sc0 only -> bypass L1, cache in XCD L2 (co-XCD amortization). Result
// NOT valid until manual s_waitcnt.
__device__ __forceinline__ u32x4 ldg_sc0_x4(const u32* p) {
  u32x4 r;
  asm volatile("global_load_dwordx4 %0, %1, off sc0" : "=v"(r) : "v"(p));
  return r;
}
#define WAITV24 do { asm volatile("s_waitcnt vmcnt(24)" ::: "memory"); \
                     __builtin_amdgcn_sched_barrier(0); } while (0)
#define WAITV16 do { asm volatile("s_waitcnt vmcnt(16)" ::: "memory"); \
                     __builtin_amdgcn_sched_barrier(0); } while (0)
#define WAITV8  do { asm volatile("s_waitcnt vmcnt(8)" ::: "memory");  \
                     __builtin_amdgcn_sched_barrier(0); } while (0)
#define WAITV0  do { asm volatile("s_waitcnt vmcnt(0)" ::: "memory");  \
                     __builtin_amdgcn_sched_barrier(0); } while (0)

// lane holds gate `gate` value v for its (b,unit); recover all 4 gates via shfl
__device__ __forceinline__ float gate_update(float pre, float& c, int gate) {
  float v = (gate == 2) ? tanhf_(pre) : sigmoidf_(pre);
  float vB = __shfl_xor(v, 4);
  float vC = __shfl_xor(v, 8);
  float vD = __shfl_xor(vB, 8);
  float i_ = (gate & 2) ? ((gate & 1) ? vD : vC) : ((gate & 1) ? vB : v);
  float f_ = (gate & 2) ? ((gate & 1) ? vC : vD) : ((gate & 1) ? v : vB);
  float g_ = (gate & 2) ? ((gate & 1) ? vB : v) : ((gate & 1) ? vD : vC);
  float o_ = (gate & 2) ? ((gate & 1) ? v : vB) : ((gate & 1) ? vC : vD);
  float cn = f_ * c + i_ * g_;
  c = cn;
  return o_ * tanhf_(cn);
}

// ---------------- K0: lengths -> tstar / padflag ----------------
__global__ void prep_kernel(const int* __restrict__ x, int* __restrict__ tstar,
                            int* __restrict__ padflag) {
  int b = threadIdx.x;
  if (b < Bn) {
    int len = 0;
    for (int t = 0; t < Tn; ++t) len += (x[b * Tn + t] != PADIDX) ? 1 : 0;
    int ts = (len > 0) ? (len - 1) : (Tn - 1);  // jax wraps index -1
    tstar[b] = ts;
    padflag[b] = (x[b * Tn + ts] == PADIDX) ? 1 : 0;
  }
}

// ---------------- K1: inp[t][b][k] = bf16(embed[x[b,t]][k]), k>=300 -> 0 ----
__global__ void gather_kernel(const int* __restrict__ x, const float* __restrict__ embed,
                              unsigned short* __restrict__ inp) {
  int idx = blockIdx.x * 256 + threadIdx.x;   // total = Tn*Bn*EPn
  int k = idx % EPn;
  int rem = idx / EPn;          // t*Bn + b
  int b = rem & (Bn - 1);
  int t = rem >> 7;
  int tok = x[b * Tn + t];
  float v = (k < En) ? embed[(size_t)tok * En + k] : 0.f;
  inp[idx] = f2bf(v);
}

// ---------------- K2: persistent LSTM scan ----------------
// 256 blocks x 256 thr (4 waves). group = bid>>7 (64 batches); 128 col-blocks/group,
// each 8 hidden units (32 gate cols). LDS: W_hh hi/lo (128 KB) + W_ih (20 KB), all
// in CONTIGUOUS per-wave-instruction layout (1024 B per ds_read_b128, 0 conflicts,
// R7-measured) and fence-immune. h: packed u32 (bf16 hi|lo<<16), 16-buffer rotation;
// stores sc0sc1 (write-through L3), loads sc0 (L2-fill); acquire-fence every 8 steps
// kills stale h lines before address reuse at t+16 (weights now immune in LDS).
// Sync: per-block monotone flag; ONLY WAVE 0 polls, others HW-sleep at barrier.
__global__ __launch_bounds__(256, 1) void lstm_scan(
    const float* __restrict__ Whh, const float* __restrict__ Wih,
    const float* __restrict__ bih, const float* __restrict__ bhh,
    const unsigned short* __restrict__ inp, const int* __restrict__ tstar,
    const int* __restrict__ padflag, u32* __restrict__ h_pk,
    float* __restrict__ hsel, u32* __restrict__ flags) {
  // elem index i = ks*1024 + ct*512 + lq*128 + lr*8 + j  (contig per (ks,ct) read)
  __shared__ unsigned short lds_hi[32768];   // 64 KB  W_hh hi
  __shared__ unsigned short lds_lo[32768];   // 64 KB  W_hh lo
  __shared__ unsigned short lds_ih[10240];   // 20 KB  W_ih (ks 0..9)

  const int bid = blockIdx.x;
  const int group = bid >> 7;              // 0: batches 0-63, 1: batches 64-127
  const int cb = bid & 127;                // col-block within group
  const int u0 = cb * 8;                   // 8 hidden units per block
  const int tid = threadIdx.x;

  // --- W_hh slice -> LDS hi/lo, fragment-linear ---
  for (int i = tid; i < 32768; i += 256) {
    int j = i & 7, lr = (i >> 3) & 15, lq = (i >> 7) & 3, ct = (i >> 9) & 1, ks = i >> 10;
    int col = (lr >> 2) * Hn + u0 + (lr & 3) + ct * 4;
    int k = ks * 32 + lq * 8 + j;
    float w = Whh[(size_t)col * Hn + k];
    unsigned short hi = f2bf(w);
    lds_hi[i] = hi;
    lds_lo[i] = f2bf(w - bf2f(hi));
  }
  // --- W_ih slice -> LDS, same fragment-linear layout, K padded to 320 ---
  for (int i = tid; i < 10240; i += 256) {
    int j = i & 7, lr = (i >> 3) & 15, lq = (i >> 7) & 3, ct = (i >> 9) & 1, ks = i >> 10;
    int col = (lr >> 2) * Hn + u0 + (lr & 3) + ct * 4;
    int k = ks * 32 + lq * 8 + j;
    float v = (k < En) ? Wih[(size_t)col * En + k] : 0.f;
    lds_ih[i] = f2bf(v);
  }
  __syncthreads();

  const int wv = tid >> 6, l = tid & 63;
  const int lr = l & 15;                    // A-row (batch) / D-col in tile
  const int lq = l >> 4;                    // quadrant
  const int usub = lr & 3, gate = lr >> 2;
  const int b0w = group * 64 + wv * 16;     // this wave's 16 batch rows
  const int col0 = gate * Hn + u0 + usub;   // ct=0 gate column; ct=1 is col0+4
  const float bias0 = bih[col0] + bhh[col0];
  const float bias1 = bih[col0 + 4] + bhh[col0 + 4];
  const u32 lfrag = (u32)(lq * 256 + lr * 16);   // per-lane byte in 1 KB fragment
  u32* const fg = flags + (group << 7);     // group's 128 per-block flags

  int tsr[4], pfr[4];
#pragma unroll
  for (int r = 0; r < 4; ++r) {
    int b = b0w + lq * 4 + r;
    tsr[r] = tstar[b];
    pfr[r] = padflag[b];
  }
  float creg0[4] = {0.f, 0.f, 0.f, 0.f};
  float creg1[4] = {0.f, 0.f, 0.f, 0.f};

  const char* base_hi = (const char*)lds_hi;
  const char* base_lo = (const char*)lds_lo;
  const char* base_ih = (const char*)lds_ih;

  u32x4 qa[4][4][2];  // h prefetch: 4 chunks x 4 ks x 32B

#define ISSUE_A(BUF, C)                                                          \
  _Pragma("unroll") for (int ii = 0; ii < 4; ++ii) {                             \
    const u32* p = hbase + ((C) * 4 + ii) * 32;                                  \
    qa[BUF][ii][0] = ldg_sc0_x4(p);                                              \
    qa[BUF][ii][1] = ldg_sc0_x4(p + 4);                                          \
  }
#define BODY_(BUF, C)                                                            \
  _Pragma("unroll") for (int ii = 0; ii < 4; ++ii) {                             \
    int ks = (C) * 4 + ii;                                                       \
    u32x4 q0 = qa[BUF][ii][0], q1 = qa[BUF][ii][1];                              \
    u32x4 vh, vl;                                                                \
    vh[0] = __builtin_amdgcn_perm(q0[1], q0[0], 0x05040100u);                    \
    vh[1] = __builtin_amdgcn_perm(q0[3], q0[2], 0x05040100u);                    \
    vh[2] = __builtin_amdgcn_perm(q1[1], q1[0], 0x05040100u);                    \
    vh[3] = __builtin_amdgcn_perm(q1[3], q1[2], 0x05040100u);                    \
    vl[0] = __builtin_amdgcn_perm(q0[1], q0[0], 0x07060302u);                    \
    vl[1] = __builtin_amdgcn_perm(q0[3], q0[2], 0x07060302u);                    \
    vl[2] = __builtin_amdgcn_perm(q1[1], q1[0], 0x07060302u);                    \
    vl[3] = __builtin_amdgcn_perm(q1[3], q1[2], 0x07060302u);                    \
    s16x8 ahi = __builtin_bit_cast(s16x8, vh);                                   \
    s16x8 alo = __builtin_bit_cast(s16x8, vl);                                   \
    u32 ob = (u32)ks * 2048 + lfrag;                                             \
    s16x8 bh0 = *(const s16x8*)(base_hi + ob);                                   \
    s16x8 bl0 = *(const s16x8*)(base_lo + ob);                                   \
    s16x8 bh1 = *(const s16x8*)(base_hi + ob + 1024);                            \
    s16x8 bl1 = *(const s16x8*)(base_lo + ob + 1024);                            \
    acc0 = __builtin_amdgcn_mfma_f32_16x16x32_bf16(ahi, bh0, acc0, 0, 0, 0);     \
    acc1 = __builtin_amdgcn_mfma_f32_16x16x32_bf16(ahi, bh1, acc1, 0, 0, 0);     \
    acc0 = __builtin_amdgcn_mfma_f32_16x16x32_bf16(alo, bh0, acc0, 0, 0, 0);     \
    acc1 = __builtin_amdgcn_mfma_f32_16x16x32_bf16(alo, bh1, acc1, 0, 0, 0);     \
    acc0 = __builtin_amdgcn_mfma_f32_16x16x32_bf16(ahi, bl0, acc0, 0, 0, 0);     \
    acc1 = __builtin_amdgcn_mfma_f32_16x16x32_bf16(ahi, bl1, acc1, 0, 0, 0);     \
  }

  for (int t = 0; t < Tn; ++t) {
    f32x4 acc0 = {bias0, bias0, bias0, bias0};
    f32x4 acc1 = {bias1, bias1, bias1, bias1};

    // ---- x-projection FIRST (h-independent; W from LDS, only inp from global) ----
    const unsigned short* ip = inp + ((size_t)t * Bn + b0w + lr) * EPn + lq * 8;
#pragma unroll
    for (int ks = 0; ks < 10; ++ks) {
      s16x8 a = *(const s16x8*)(ip + ks * 32);
      u32 ob = (u32)ks * 2048 + lfrag;
      s16x8 b0 = *(const s16x8*)(base_ih + ob);
      s16x8 b1 = *(const s16x8*)(base_ih + ob + 1024);
      acc0 = __builtin_amdgcn_mfma_f32_16x16x32_bf16(a, b0, acc0, 0, 0, 0);
      acc1 = __builtin_amdgcn_mfma_f32_16x16x32_bf16(a, b1, acc1, 0, 0, 0);
    }

    // ---- release: wave 0 polls the 128 flags; waves 1-3 sleep at the barrier ----
    if (t) {
      if (wv == 0) {
        u32 spins = 0;
        for (;;) {
          u32 f0 = LDQ32(fg + l);
          u32 f1 = LDQ32(fg + 64 + l);
          if (__ballot((f0 >= (u32)t) & (f1 >= (u32)t)) == ~0ull) break;
          __builtin_amdgcn_s_sleep(1);
          if (++spins > 400000u) break;  // watchdog: dead unless deadlock
        }
      }
      __syncthreads();
    }
    WAITV0;  // clean vmcnt before counted prefetch chain

    // ---- recurrent K=1024: 8 chunks x 4 ks, 4-deep prefetch, counted vmcnt ----
    const u32* hbase = h_pk + (size_t)(t & (NROT - 1)) * (Bn * Hn) +
                       (size_t)(b0w + lr) * Hn + lq * 8;
    ISSUE_A(0, 0) ISSUE_A(1, 1) ISSUE_A(2, 2) ISSUE_A(3, 3)
    WAITV24; BODY_(0, 0) ISSUE_A(0, 4)
    WAITV24; BODY_(1, 1) ISSUE_A(1, 5)
    WAITV24; BODY_(2, 2) ISSUE_A(2, 6)
    WAITV24; BODY_(3, 3) ISSUE_A(3, 7)
    WAITV24; BODY_(0, 4)
    WAITV16; BODY_(1, 5)
    WAITV8;  BODY_(2, 6)
    WAITV0;  BODY_(3, 7)

    // ---- gates + state update (both col-tiles) ----
    u32* const hout = h_pk + (size_t)((t + 1) & (NROT - 1)) * (Bn * Hn);
#pragma unroll
    for (int r = 0; r < 4; ++r) {
      float h0 = gate_update(acc0[r], creg0[r], gate);
      float h1 = gate_update(acc1[r], creg1[r], gate);
      unsigned short h0h = f2bf(h0);
      unsigned short h0l = f2bf(h0 - bf2f(h0h));
      unsigned short h1h = f2bf(h1);
      unsigned short h1l = f2bf(h1 - bf2f(h1h));
      if (gate == 0) {
        int b = b0w + lq * 4 + r;
        u32* rowp = hout + (size_t)b * Hn;
        ST32(rowp + u0 + usub, (u32)h0h | ((u32)h0l << 16));
        ST32(rowp + u0 + usub + 4, (u32)h1h | ((u32)h1l << 16));
        if (t == tsr[r]) {
          hsel[(size_t)b * Hn + u0 + usub] = pfr[r] ? 0.f : h0;
          hsel[(size_t)b * Hn + u0 + usub + 4] = pfr[r] ? 0.f : h1;
        }
      }
    }

    // ---- arrival: barrier (compiler drains each wave's vmcnt), publish flag ----
    __syncthreads();
    if (tid == 0) ST32(fg + cb, (u32)(t + 1));
    // every 8 steps: invalidate local L2/L1 h copies (weights are LDS-immune);
    // guarantees no stale h line survives to the address's reuse at t+16
    if ((t & 7) == 7) __builtin_amdgcn_fence(__ATOMIC_ACQUIRE, "agent");
  }
#undef ISSUE_A
#undef BODY_
}

// ---------------- K3: out[b][o] = hsel[b]·W_out[o] + b_out[o] ----------------
__global__ void head_kernel(const float* __restrict__ hsel, const float* __restrict__ Wout,
                            const float* __restrict__ bout, float* __restrict__ out) {
  int b = blockIdx.x;
  int l = threadIdx.x;  // 64 threads
  float s0 = 0.f, s1 = 0.f, s2 = 0.f;
  for (int j = l; j < Hn; j += 64) {
    float h = hsel[(size_t)b * Hn + j];
    s0 += h * Wout[j];
    s1 += h * Wout[Hn + j];
    s2 += h * Wout[2 * Hn + j];
  }
#pragma unroll
  for (int m = 32; m; m >>= 1) {
    s0 += __shfl_xor(s0, m);
    s1 += __shfl_xor(s1, m);
    s2 += __shfl_xor(s2, m);
  }
  if (l == 0) {
    out[b * 3 + 0] = s0 + bout[0];
    out[b * 3 + 1] = s1 + bout[1];
    out[b * 3 + 2] = s2 + bout[2];
  }
}

extern "C" void kernel_launch(void* const* d_in, const int* in_sizes, int n_in,
                              void* d_out, int out_size, void* d_ws, size_t ws_size,
                              hipStream_t stream) {
  const int* x = (const int*)d_in[0];
  const float* embed = (const float*)d_in[1];
  const float* Wih = (const float*)d_in[2];
  const float* Whh = (const float*)d_in[3];
  const float* bih = (const float*)d_in[4];
  const float* bhh = (const float*)d_in[5];
  const float* Wout = (const float*)d_in[6];
  const float* bout = (const float*)d_in[7];
  float* out = (float*)d_out;

  // ws layout
  const size_t INP_BYTES = (size_t)Tn * Bn * EPn * 2;        // 20,971,520
  const size_t HPK_BYTES = (size_t)NROT * Bn * Hn * 4;       //  8,388,608
  const size_t HSEL_BYTES = (size_t)Bn * Hn * 4;             //    524,288
  char* p = (char*)d_ws;
  unsigned short* inp = (unsigned short*)p;             p += INP_BYTES;
  u32* h_pk = (u32*)p;                                  p += HPK_BYTES;
  float* hsel = (float*)p;                              p += HSEL_BYTES;
  int* tstar = (int*)p;                                 p += 512;
  int* padflag = (int*)p;                               p += 512;
  u32* flags = (u32*)p;                                 p += 1024;

  // per-launch init: h(0) = 0 (rotation slot 0), flags = 0 (self-contained replay)
  hipMemsetAsync(h_pk, 0, (size_t)Bn * Hn * 4, stream);
  hipMemsetAsync(flags, 0, 1024, stream);

  prep_kernel<<<1, 128, 0, stream>>>(x, tstar, padflag);
  gather_kernel<<<(Tn * Bn * EPn) / 256, 256, 0, stream>>>(x, embed, inp);
  lstm_scan<<<NBLK, 256, 0, stream>>>(Whh, Wih, bih, bhh, inp, tstar, padflag,
                                      h_pk, hsel, flags);
  head_kernel<<<Bn, 64, 0, stream>>>(hsel, Wout, bout, out);
}

// Round 10
// 2155.914 us; speedup vs baseline: 1.7148x; 1.4501x over previous
//
#include <hip/hip_runtime.h>
#include <stdint.h>

#define Bn 128
#define Tn 256
#define En 300
#define Hn 1024
#define PADIDX 1
#define NBLK 256         // 2 groups x 128 col-blocks
#define NROT 16          // h buffer rotation depth (fresh address per step)

typedef short s16x8 __attribute__((ext_vector_type(8)));
typedef float f32x4 __attribute__((ext_vector_type(4)));
typedef unsigned int u32;
typedef u32 u32x4 __attribute__((ext_vector_type(4)));

#define LDQ32(p) __hip_atomic_load((p), __ATOMIC_RELAXED, __HIP_MEMORY_SCOPE_SYSTEM)
#define ST32(p, v) __hip_atomic_store((p), (v), __ATOMIC_RELAXED, __HIP_MEMORY_SCOPE_SYSTEM)

__device__ __forceinline__ unsigned short f2bf(float f) {
  u32 u = __builtin_bit_cast(u32, f);
  u32 r = (u + 0x7fffu + ((u >> 16) & 1u)) >> 16;  // RNE
  return (unsigned short)r;
}
__device__ __forceinline__ float bf2f(unsigned short h) {
  u32 u = ((u32)h) << 16;
  return __builtin_bit_cast(float, u);
}
__device__ __forceinline__ float sigmoidf_(float x) { return 1.f / (1.f + __expf(-x)); }
__device__ __forceinline__ float tanhf_(float x) { return 1.f - 2.f / (__expf(2.f * x) + 1.f); }

// h load: sc0 only -> bypass L1, cache in XCD L2 (co-XCD amortization). Result
// NOT valid until manual s_waitcnt.
__device__ __forceinline__ u32x4 ldg_sc0_x4(const u32* p) {
  u32x4 r;
  asm volatile("global_load_dwordx4 %0, %1, off sc0" : "=v"(r) : "v"(p));
  return r;
}
#define WAITV24 do { asm volatile("s_waitcnt vmcnt(24)" ::: "memory"); \
                     __builtin_amdgcn_sched_barrier(0); } while (0)
#define WAITV16 do { asm volatile("s_waitcnt vmcnt(16)" ::: "memory"); \
                     __builtin_amdgcn_sched_barrier(0); } while (0)
#define WAITV8  do { asm volatile("s_waitcnt vmcnt(8)" ::: "memory");  \
                     __builtin_amdgcn_sched_barrier(0); } while (0)
#define WAITV0  do { asm volatile("s_waitcnt vmcnt(0)" ::: "memory");  \
                     __builtin_amdgcn_sched_barrier(0); } while (0)

// lane holds gate `gate` value v for its (b,unit); recover all 4 gates via shfl
__device__ __forceinline__ float gate_update(float pre, float& c, int gate) {
  float v = (gate == 2) ? tanhf_(pre) : sigmoidf_(pre);
  float vB = __shfl_xor(v, 4);
  float vC = __shfl_xor(v, 8);
  float vD = __shfl_xor(vB, 8);
  float i_ = (gate & 2) ? ((gate & 1) ? vD : vC) : ((gate & 1) ? vB : v);
  float f_ = (gate & 2) ? ((gate & 1) ? vC : vD) : ((gate & 1) ? v : vB);
  float g_ = (gate & 2) ? ((gate & 1) ? vB : v) : ((gate & 1) ? vD : vC);
  float o_ = (gate & 2) ? ((gate & 1) ? v : vB) : ((gate & 1) ? vC : vD);
  float cn = f_ * c + i_ * g_;
  c = cn;
  return o_ * tanhf_(cn);
}

// ---------------- K0: lengths -> tstar / padflag ----------------
__global__ void prep_kernel(const int* __restrict__ x, int* __restrict__ tstar,
                            int* __restrict__ padflag) {
  int b = threadIdx.x;
  if (b < Bn) {
    int len = 0;
    for (int t = 0; t < Tn; ++t) len += (x[b * Tn + t] != PADIDX) ? 1 : 0;
    int ts = (len > 0) ? (len - 1) : (Tn - 1);  // jax wraps index -1
    tstar[b] = ts;
    padflag[b] = (x[b * Tn + ts] == PADIDX) ? 1 : 0;
  }
}

// ---------------- K1: embedding gather, A-fragment-linear (R5/R9-verified) ------
// inp2[((t*8 + rg)*10 + ks)*64 + l][8] ; rg = group*4+wv ; b = rg*16+(l&15) ;
// k = ks*32 + (l>>4)*8 + jj ; zero-padded past 300.
__global__ void gather2_kernel(const int* __restrict__ x, const float* __restrict__ embed,
                               unsigned short* __restrict__ inp2) {
  int idx = blockIdx.x * 256 + threadIdx.x;  // total 256*8*10*512 = 10,485,760
  int jj = idx & 7;
  int tmp = idx >> 3;
  int l = tmp & 63; tmp >>= 6;
  int ks = tmp % 10; tmp /= 10;
  int rg = tmp & 7;
  int t = tmp >> 3;
  int b = rg * 16 + (l & 15);
  int k = ks * 32 + (l >> 4) * 8 + jj;
  int tok = x[b * Tn + t];
  float v = (k < En) ? embed[(size_t)tok * En + k] : 0.f;
  inp2[idx] = f2bf(v);
}

// ---------------- K2: persistent LSTM scan ----------------
// 256 blocks x 256 thr (4 waves). group = bid>>7 (64 batches); 128 col-blocks/group,
// each 8 hidden units (32 gate cols). LDS: W_hh hi/lo (128 KB) + W_ih (20 KB) in
// 0-conflict fragment-linear layout (R7/R8-measured).
// h layout BLOCK-MAJOR: flat u32 index = cb'*1024 + b*8 + usub (cb'=unit/8) ->
// reader's 8 k-values per lane are one contiguous 32B run; 16 lanes form 512B
// segments (coalesced). Stores: R8's PROVEN per-lane ST32 atomics (scattered but
// within a 2KB window) + barrier drain + tid0 flag publish. Loads sc0 (L2-fill).
// Rotation NROT=16 + acquire-fence every 8 steps kills stale lines before reuse.
__global__ __launch_bounds__(256, 1) void lstm_scan(
    const float* __restrict__ Whh, const float* __restrict__ Wih,
    const float* __restrict__ bih, const float* __restrict__ bhh,
    const unsigned short* __restrict__ inp2, const int* __restrict__ tstar,
    const int* __restrict__ padflag, u32* __restrict__ h_pk,
    float* __restrict__ hsel, u32* __restrict__ flags) {
  // elem index i = ks*1024 + ct*512 + lq*128 + lr*8 + j  (contig per (ks,ct) read)
  __shared__ unsigned short lds_hi[32768];   // 64 KB  W_hh hi
  __shared__ unsigned short lds_lo[32768];   // 64 KB  W_hh lo
  __shared__ unsigned short lds_ih[10240];   // 20 KB  W_ih (ks 0..9)

  const int bid = blockIdx.x;
  const int group = bid >> 7;              // 0: batches 0-63, 1: batches 64-127
  const int cb = bid & 127;                // col-block within group
  const int u0 = cb * 8;                   // 8 hidden units per block
  const int tid = threadIdx.x;

  // --- W_hh slice -> LDS hi/lo, fragment-linear ---
  for (int i = tid; i < 32768; i += 256) {
    int j = i & 7, lr = (i >> 3) & 15, lq = (i >> 7) & 3, ct = (i >> 9) & 1, ks = i >> 10;
    int col = (lr >> 2) * Hn + u0 + (lr & 3) + ct * 4;
    int k = ks * 32 + lq * 8 + j;
    float w = Whh[(size_t)col * Hn + k];
    unsigned short hi = f2bf(w);
    lds_hi[i] = hi;
    lds_lo[i] = f2bf(w - bf2f(hi));
  }
  // --- W_ih slice -> LDS, same fragment-linear layout, K padded to 320 ---
  for (int i = tid; i < 10240; i += 256) {
    int j = i & 7, lr = (i >> 3) & 15, lq = (i >> 7) & 3, ct = (i >> 9) & 1, ks = i >> 10;
    int col = (lr >> 2) * Hn + u0 + (lr & 3) + ct * 4;
    int k = ks * 32 + lq * 8 + j;
    float v = (k < En) ? Wih[(size_t)col * En + k] : 0.f;
    lds_ih[i] = f2bf(v);
  }
  __syncthreads();

  const int wv = tid >> 6, l = tid & 63;
  const int lr = l & 15;                    // A-row (batch) / D-col in tile
  const int lq = l >> 4;                    // quadrant
  const int usub = lr & 3, gate = lr >> 2;
  const int b0w = group * 64 + wv * 16;     // this wave's 16 batch rows
  const int col0 = gate * Hn + u0 + usub;   // ct=0 gate column; ct=1 is col0+4
  const float bias0 = bih[col0] + bhh[col0];
  const float bias1 = bih[col0 + 4] + bhh[col0 + 4];
  const u32 lfrag = (u32)(lq * 256 + lr * 16);   // per-lane byte in 1 KB fragment
  u32* const fg = flags + (group << 7);     // group's 128 per-block flags

  int tsr[4], pfr[4];
#pragma unroll
  for (int r = 0; r < 4; ++r) {
    int b = b0w + lq * 4 + r;
    tsr[r] = tstar[b];
    pfr[r] = padflag[b];
  }
  float creg0[4] = {0.f, 0.f, 0.f, 0.f};
  float creg1[4] = {0.f, 0.f, 0.f, 0.f};

  const char* base_hi = (const char*)lds_hi;
  const char* base_lo = (const char*)lds_lo;
  const char* base_ih = (const char*)lds_ih;

  u32x4 qa[4][4][2];  // h prefetch: 4 chunks x 4 ks x 32B

// block-major addressing: flat u32 = (ks*4 + lq)*1024 + b*8  (+usub)
#define ISSUE_A(BUF, C)                                                          \
  _Pragma("unroll") for (int ii = 0; ii < 4; ++ii) {                             \
    const u32* p = hbase + ((C) * 4 + ii) * 4096;                                \
    qa[BUF][ii][0] = ldg_sc0_x4(p);                                              \
    qa[BUF][ii][1] = ldg_sc0_x4(p + 4);                                          \
  }
#define BODY_(BUF, C)                                                            \
  _Pragma("unroll") for (int ii = 0; ii < 4; ++ii) {                             \
    int ks = (C) * 4 + ii;                                                       \
    u32x4 q0 = qa[BUF][ii][0], q1 = qa[BUF][ii][1];                              \
    u32x4 vh, vl;                                                                \
    vh[0] = __builtin_amdgcn_perm(q0[1], q0[0], 0x05040100u);                    \
    vh[1] = __builtin_amdgcn_perm(q0[3], q0[2], 0x05040100u);                    \
    vh[2] = __builtin_amdgcn_perm(q1[1], q1[0], 0x05040100u);                    \
    vh[3] = __builtin_amdgcn_perm(q1[3], q1[2], 0x05040100u);                    \
    vl[0] = __builtin_amdgcn_perm(q0[1], q0[0], 0x07060302u);                    \
    vl[1] = __builtin_amdgcn_perm(q0[3], q0[2], 0x07060302u);                    \
    vl[2] = __builtin_amdgcn_perm(q1[1], q1[0], 0x07060302u);                    \
    vl[3] = __builtin_amdgcn_perm(q1[3], q1[2], 0x07060302u);                    \
    s16x8 ahi = __builtin_bit_cast(s16x8, vh);                                   \
    s16x8 alo = __builtin_bit_cast(s16x8, vl);                                   \
    u32 ob = (u32)ks * 2048 + lfrag;                                             \
    s16x8 bh0 = *(const s16x8*)(base_hi + ob);                                   \
    s16x8 bl0 = *(const s16x8*)(base_lo + ob);                                   \
    s16x8 bh1 = *(const s16x8*)(base_hi + ob + 1024);                            \
    s16x8 bl1 = *(const s16x8*)(base_lo + ob + 1024);                            \
    acc0 = __builtin_amdgcn_mfma_f32_16x16x32_bf16(ahi, bh0, acc0, 0, 0, 0);     \
    acc1 = __builtin_amdgcn_mfma_f32_16x16x32_bf16(ahi, bh1, acc1, 0, 0, 0);     \
    acc0 = __builtin_amdgcn_mfma_f32_16x16x32_bf16(alo, bh0, acc0, 0, 0, 0);     \
    acc1 = __builtin_amdgcn_mfma_f32_16x16x32_bf16(alo, bh1, acc1, 0, 0, 0);     \
    acc0 = __builtin_amdgcn_mfma_f32_16x16x32_bf16(ahi, bl0, acc0, 0, 0, 0);     \
    acc1 = __builtin_amdgcn_mfma_f32_16x16x32_bf16(ahi, bl1, acc1, 0, 0, 0);     \
  }

  for (int t = 0; t < Tn; ++t) {
    f32x4 acc0 = {bias0, bias0, bias0, bias0};
    f32x4 acc1 = {bias1, bias1, bias1, bias1};

    // ---- x-projection FIRST (h-independent; W + inp both conflict-free) ----
    const unsigned short* ipA =
        inp2 + ((size_t)(t * 8 + (group * 4 + wv)) * 10) * 512 + l * 8;
#pragma unroll
    for (int ks = 0; ks < 10; ++ks) {
      s16x8 a = *(const s16x8*)(ipA + ks * 512);
      u32 ob = (u32)ks * 2048 + lfrag;
      s16x8 b0 = *(const s16x8*)(base_ih + ob);
      s16x8 b1 = *(const s16x8*)(base_ih + ob + 1024);
      acc0 = __builtin_amdgcn_mfma_f32_16x16x32_bf16(a, b0, acc0, 0, 0, 0);
      acc1 = __builtin_amdgcn_mfma_f32_16x16x32_bf16(a, b1, acc1, 0, 0, 0);
    }

    // ---- release: wave 0 polls the 128 flags; waves 1-3 sleep at the barrier ----
    if (t) {
      if (wv == 0) {
        u32 spins = 0;
        for (;;) {
          u32 f0 = LDQ32(fg + l);
          u32 f1 = LDQ32(fg + 64 + l);
          if (__ballot((f0 >= (u32)t) & (f1 >= (u32)t)) == ~0ull) break;
          __builtin_amdgcn_s_sleep(1);
          if (++spins > 400000u) break;  // watchdog: dead unless deadlock
        }
      }
      __syncthreads();
    }
    WAITV0;  // clean vmcnt before counted prefetch chain

    // ---- recurrent K=1024: 8 chunks x 4 ks, 4-deep prefetch, counted vmcnt ----
    const u32* hbase = h_pk + (size_t)(t & (NROT - 1)) * (Bn * Hn) +
                       (u32)(lq * 1024 + (b0w + lr) * 8);
    ISSUE_A(0, 0) ISSUE_A(1, 1) ISSUE_A(2, 2) ISSUE_A(3, 3)
    WAITV24; BODY_(0, 0) ISSUE_A(0, 4)
    WAITV24; BODY_(1, 1) ISSUE_A(1, 5)
    WAITV24; BODY_(2, 2) ISSUE_A(2, 6)
    WAITV24; BODY_(3, 3) ISSUE_A(3, 7)
    WAITV24; BODY_(0, 4)
    WAITV16; BODY_(1, 5)
    WAITV8;  BODY_(2, 6)
    WAITV0;  BODY_(3, 7)

    // ---- gates + state update; per-lane ST32 into block-major slice (R8 path) ----
    u32* const hout = h_pk + (size_t)((t + 1) & (NROT - 1)) * (Bn * Hn);
#pragma unroll
    for (int r = 0; r < 4; ++r) {
      float h0 = gate_update(acc0[r], creg0[r], gate);
      float h1 = gate_update(acc1[r], creg1[r], gate);
      unsigned short h0h = f2bf(h0);
      unsigned short h0l = f2bf(h0 - bf2f(h0h));
      unsigned short h1h = f2bf(h1);
      unsigned short h1l = f2bf(h1 - bf2f(h1h));
      if (gate == 0) {
        int b = b0w + lq * 4 + r;
        u32* slice = hout + (u32)(cb * 1024 + b * 8);
        ST32(slice + usub, (u32)h0h | ((u32)h0l << 16));
        ST32(slice + usub + 4, (u32)h1h | ((u32)h1l << 16));
        if (t == tsr[r]) {
          hsel[(size_t)b * Hn + u0 + usub] = pfr[r] ? 0.f : h0;
          hsel[(size_t)b * Hn + u0 + usub + 4] = pfr[r] ? 0.f : h1;
        }
      }
    }

    // ---- arrival: barrier (compiler drains each wave's vmcnt), publish flag ----
    __syncthreads();
    if (tid == 0) ST32(fg + cb, (u32)(t + 1));
    // every 8 steps: invalidate local L2/L1 h copies (weights are LDS-immune);
    // guarantees no stale h line survives to the address's reuse at t+16
    if ((t & 7) == 7) __builtin_amdgcn_fence(__ATOMIC_ACQUIRE, "agent");
  }
#undef ISSUE_A
#undef BODY_
}

// ---------------- K3: out[b][o] = hsel[b]·W_out[o] + b_out[o] ----------------
__global__ void head_kernel(const float* __restrict__ hsel, const float* __restrict__ Wout,
                            const float* __restrict__ bout, float* __restrict__ out) {
  int b = blockIdx.x;
  int l = threadIdx.x;  // 64 threads
  float s0 = 0.f, s1 = 0.f, s2 = 0.f;
  for (int j = l; j < Hn; j += 64) {
    float h = hsel[(size_t)b * Hn + j];
    s0 += h * Wout[j];
    s1 += h * Wout[Hn + j];
    s2 += h * Wout[2 * Hn + j];
  }
#pragma unroll
  for (int m = 32; m; m >>= 1) {
    s0 += __shfl_xor(s0, m);
    s1 += __shfl_xor(s1, m);
    s2 += __shfl_xor(s2, m);
  }
  if (l == 0) {
    out[b * 3 + 0] = s0 + bout[0];
    out[b * 3 + 1] = s1 + bout[1];
    out[b * 3 + 2] = s2 + bout[2];
  }
}

extern "C" void kernel_launch(void* const* d_in, const int* in_sizes, int n_in,
                              void* d_out, int out_size, void* d_ws, size_t ws_size,
                              hipStream_t stream) {
  const int* x = (const int*)d_in[0];
  const float* embed = (const float*)d_in[1];
  const float* Wih = (const float*)d_in[2];
  const float* Whh = (const float*)d_in[3];
  const float* bih = (const float*)d_in[4];
  const float* bhh = (const float*)d_in[5];
  const float* Wout = (const float*)d_in[6];
  const float* bout = (const float*)d_in[7];
  float* out = (float*)d_out;

  // ws layout
  const size_t INP2_BYTES = (size_t)Tn * 8 * 10 * 512 * 2;   // 20,971,520
  const size_t HPK_BYTES = (size_t)NROT * Bn * Hn * 4;       //  8,388,608
  const size_t HSEL_BYTES = (size_t)Bn * Hn * 4;             //    524,288
  char* p = (char*)d_ws;
  unsigned short* inp2 = (unsigned short*)p;            p += INP2_BYTES;
  u32* h_pk = (u32*)p;                                  p += HPK_BYTES;
  float* hsel = (float*)p;                              p += HSEL_BYTES;
  int* tstar = (int*)p;                                 p += 512;
  int* padflag = (int*)p;                               p += 512;
  u32* flags = (u32*)p;                                 p += 1024;

  // per-launch init: h(0) = 0 (rotation slot 0), flags = 0 (self-contained replay)
  hipMemsetAsync(h_pk, 0, (size_t)Bn * Hn * 4, stream);
  hipMemsetAsync(flags, 0, 1024, stream);

  prep_kernel<<<1, 128, 0, stream>>>(x, tstar, padflag);
  gather2_kernel<<<40960, 256, 0, stream>>>(x, embed, inp2);
  lstm_scan<<<NBLK, 256, 0, stream>>>(Whh, Wih, bih, bhh, inp2, tstar, padflag,
                                      h_pk, hsel, flags);
  head_kernel<<<Bn, 64, 0, stream>>>(hsel, Wout, bout, out);
}

// Round 12
// 2128.407 us; speedup vs baseline: 1.7370x; 1.0129x over previous
//
#include <hip/hip_runtime.h>
#include <stdint.h>

#define Bn 128
#define Tn 256
#define En 300
#define Hn 1024
#define PADIDX 1
#define NBLK 256         // 2 groups x 128 col-blocks
#define NROT 16          // h buffer rotation depth (fresh address per step)

typedef short s16x8 __attribute__((ext_vector_type(8)));
typedef float f32x4 __attribute__((ext_vector_type(4)));
typedef unsigned int u32;
typedef u32 u32x4 __attribute__((ext_vector_type(4)));

#define LDQ32(p) __hip_atomic_load((p), __ATOMIC_RELAXED, __HIP_MEMORY_SCOPE_SYSTEM)
#define ST32(p, v) __hip_atomic_store((p), (v), __ATOMIC_RELAXED, __HIP_MEMORY_SCOPE_SYSTEM)

__device__ __forceinline__ unsigned short f2bf(float f) {
  u32 u = __builtin_bit_cast(u32, f);
  u32 r = (u + 0x7fffu + ((u >> 16) & 1u)) >> 16;  // RNE
  return (unsigned short)r;
}
__device__ __forceinline__ float bf2f(unsigned short h) {
  u32 u = ((u32)h) << 16;
  return __builtin_bit_cast(float, u);
}
__device__ __forceinline__ float sigmoidf_(float x) { return 1.f / (1.f + __expf(-x)); }
__device__ __forceinline__ float tanhf_(float x) { return 1.f - 2.f / (__expf(2.f * x) + 1.f); }

// h load: sc0 only -> bypass L1, cache in XCD L2 (co-XCD amortization). Result
// NOT valid until manual s_waitcnt.
__device__ __forceinline__ u32x4 ldg_sc0_x4(const u32* p) {
  u32x4 r;
  asm volatile("global_load_dwordx4 %0, %1, off sc0" : "=v"(r) : "v"(p));
  return r;
}
#define WAITV24 do { asm volatile("s_waitcnt vmcnt(24)" ::: "memory"); \
                     __builtin_amdgcn_sched_barrier(0); } while (0)
#define WAITV16 do { asm volatile("s_waitcnt vmcnt(16)" ::: "memory"); \
                     __builtin_amdgcn_sched_barrier(0); } while (0)
#define WAITV8  do { asm volatile("s_waitcnt vmcnt(8)" ::: "memory");  \
                     __builtin_amdgcn_sched_barrier(0); } while (0)
#define WAITV0  do { asm volatile("s_waitcnt vmcnt(0)" ::: "memory");  \
                     __builtin_amdgcn_sched_barrier(0); } while (0)

// lane holds gate `gate` value v for its (b,unit); recover all 4 gates via shfl
__device__ __forceinline__ float gate_update(float pre, float& c, int gate) {
  float v = (gate == 2) ? tanhf_(pre) : sigmoidf_(pre);
  float vB = __shfl_xor(v, 4);
  float vC = __shfl_xor(v, 8);
  float vD = __shfl_xor(vB, 8);
  float i_ = (gate & 2) ? ((gate & 1) ? vD : vC) : ((gate & 1) ? vB : v);
  float f_ = (gate & 2) ? ((gate & 1) ? vC : vD) : ((gate & 1) ? v : vB);
  float g_ = (gate & 2) ? ((gate & 1) ? vB : v) : ((gate & 1) ? vD : vC);
  float o_ = (gate & 2) ? ((gate & 1) ? v : vB) : ((gate & 1) ? vC : vD);
  float cn = f_ * c + i_ * g_;
  c = cn;
  return o_ * tanhf_(cn);
}

// ---------------- K0: lengths -> tstar / padflag ----------------
__global__ void prep_kernel(const int* __restrict__ x, int* __restrict__ tstar,
                            int* __restrict__ padflag) {
  int b = threadIdx.x;
  if (b < Bn) {
    int len = 0;
    for (int t = 0; t < Tn; ++t) len += (x[b * Tn + t] != PADIDX) ? 1 : 0;
    int ts = (len > 0) ? (len - 1) : (Tn - 1);  // jax wraps index -1
    tstar[b] = ts;
    padflag[b] = (x[b * Tn + ts] == PADIDX) ? 1 : 0;
  }
}

// ---------------- K1: embedding gather, A-fragment-linear (R5/R10-verified) -----
// inp2[((t*8 + rg)*10 + ks)*64 + l][8] ; rg = group*4+wv ; b = rg*16+(l&15) ;
// k = ks*32 + (l>>4)*8 + jj ; zero-padded past 300.
__global__ void gather2_kernel(const int* __restrict__ x, const float* __restrict__ embed,
                               unsigned short* __restrict__ inp2) {
  int idx = blockIdx.x * 256 + threadIdx.x;  // total 256*8*10*512 = 10,485,760
  int jj = idx & 7;
  int tmp = idx >> 3;
  int l = tmp & 63; tmp >>= 6;
  int ks = tmp % 10; tmp /= 10;
  int rg = tmp & 7;
  int t = tmp >> 3;
  int b = rg * 16 + (l & 15);
  int k = ks * 32 + (l >> 4) * 8 + jj;
  int tok = x[b * Tn + t];
  float v = (k < En) ? embed[(size_t)tok * En + k] : 0.f;
  inp2[idx] = f2bf(v);
}

// ---------------- K2: persistent LSTM scan (R10 + staggered chunk order) -------
// 256 blocks x 256 thr (4 waves). group = bid>>7 (64 batches); 128 col-blocks/group,
// each 8 hidden units (32 gate cols). LDS: W_hh hi/lo (128 KB) + W_ih (20 KB) in
// 0-conflict fragment-linear layout. h block-major packed u32 (bf16 hi|lo<<16),
// rotation NROT=16, stores per-lane ST32 sc0sc1, loads sc0 (L2-fill) — R10-proven.
// Sync: R10's global barrier (wave 0 polls 128 flags, others sleep at barrier).
// NEW vs R10: after the barrier the 8 k-chunks are visited in order (cb&7)+i mod 8
// — a pure address permutation (all data is ready post-barrier) that spreads the
// 256-block burst across 8 disjoint 32 KB h regions instead of one hot region.
__global__ __launch_bounds__(256, 1) void lstm_scan(
    const float* __restrict__ Whh, const float* __restrict__ Wih,
    const float* __restrict__ bih, const float* __restrict__ bhh,
    const unsigned short* __restrict__ inp2, const int* __restrict__ tstar,
    const int* __restrict__ padflag, u32* __restrict__ h_pk,
    float* __restrict__ hsel, u32* __restrict__ flags) {
  // elem index i = ks*1024 + ct*512 + lq*128 + lr*8 + j  (contig per (ks,ct) read)
  __shared__ unsigned short lds_hi[32768];   // 64 KB  W_hh hi
  __shared__ unsigned short lds_lo[32768];   // 64 KB  W_hh lo
  __shared__ unsigned short lds_ih[10240];   // 20 KB  W_ih (ks 0..9)

  const int bid = blockIdx.x;
  const int group = bid >> 7;              // 0: batches 0-63, 1: batches 64-127
  const int cb = bid & 127;                // col-block within group
  const int u0 = cb * 8;                   // 8 hidden units per block
  const int tid = threadIdx.x;

  // --- W_hh slice -> LDS hi/lo, fragment-linear ---
  for (int i = tid; i < 32768; i += 256) {
    int j = i & 7, lr = (i >> 3) & 15, lq = (i >> 7) & 3, ct = (i >> 9) & 1, ks = i >> 10;
    int col = (lr >> 2) * Hn + u0 + (lr & 3) + ct * 4;
    int k = ks * 32 + lq * 8 + j;
    float w = Whh[(size_t)col * Hn + k];
    unsigned short hi = f2bf(w);
    lds_hi[i] = hi;
    lds_lo[i] = f2bf(w - bf2f(hi));
  }
  // --- W_ih slice -> LDS, same fragment-linear layout, K padded to 320 ---
  for (int i = tid; i < 10240; i += 256) {
    int j = i & 7, lr = (i >> 3) & 15, lq = (i >> 7) & 3, ct = (i >> 9) & 1, ks = i >> 10;
    int col = (lr >> 2) * Hn + u0 + (lr & 3) + ct * 4;
    int k = ks * 32 + lq * 8 + j;
    float v = (k < En) ? Wih[(size_t)col * En + k] : 0.f;
    lds_ih[i] = f2bf(v);
  }
  __syncthreads();

  const int wv = tid >> 6, l = tid & 63;
  const int lr = l & 15;                    // A-row (batch) / D-col in tile
  const int lq = l >> 4;                    // quadrant
  const int usub = lr & 3, gate = lr >> 2;
  const int b0w = group * 64 + wv * 16;     // this wave's 16 batch rows
  const int col0 = gate * Hn + u0 + usub;   // ct=0 gate column; ct=1 is col0+4
  const float bias0 = bih[col0] + bhh[col0];
  const float bias1 = bih[col0 + 4] + bhh[col0 + 4];
  const u32 lfrag = (u32)(lq * 256 + lr * 16);   // per-lane byte in 1 KB fragment
  const int st = cb & 7;                    // stagger: chunk start offset
  u32* const fg = flags + (group << 7);     // group's 128 per-block flags

  int tsr[4], pfr[4];
#pragma unroll
  for (int r = 0; r < 4; ++r) {
    int b = b0w + lq * 4 + r;
    tsr[r] = tstar[b];
    pfr[r] = padflag[b];
  }
  float creg0[4] = {0.f, 0.f, 0.f, 0.f};
  float creg1[4] = {0.f, 0.f, 0.f, 0.f};

  const char* base_hi = (const char*)lds_hi;
  const char* base_lo = (const char*)lds_lo;
  const char* base_ih = (const char*)lds_ih;

  u32x4 qa[4][4][2];  // h prefetch: 4 chunk buffers x 4 ks x 32B

// block-major addressing: flat u32 = (ks*4 + lq)*1024 + b*8  (+usub)
#define ISSUE_A(BUF, C)                                                          \
  _Pragma("unroll") for (int ii = 0; ii < 4; ++ii) {                             \
    const u32* p = hbase + ((C) * 4 + ii) * 4096;                                \
    qa[BUF][ii][0] = ldg_sc0_x4(p);                                              \
    qa[BUF][ii][1] = ldg_sc0_x4(p + 4);                                          \
  }
#define BODY_(BUF, C)                                                            \
  _Pragma("unroll") for (int ii = 0; ii < 4; ++ii) {                             \
    int ks = (C) * 4 + ii;                                                       \
    u32x4 q0 = qa[BUF][ii][0], q1 = qa[BUF][ii][1];                              \
    u32x4 vh, vl;                                                                \
    vh[0] = __builtin_amdgcn_perm(q0[1], q0[0], 0x05040100u);                    \
    vh[1] = __builtin_amdgcn_perm(q0[3], q0[2], 0x05040100u);                    \
    vh[2] = __builtin_amdgcn_perm(q1[1], q1[0], 0x05040100u);                    \
    vh[3] = __builtin_amdgcn_perm(q1[3], q1[2], 0x05040100u);                    \
    vl[0] = __builtin_amdgcn_perm(q0[1], q0[0], 0x07060302u);                    \
    vl[1] = __builtin_amdgcn_perm(q0[3], q0[2], 0x07060302u);                    \
    vl[2] = __builtin_amdgcn_perm(q1[1], q1[0], 0x07060302u);                    \
    vl[3] = __builtin_amdgcn_perm(q1[3], q1[2], 0x07060302u);                    \
    s16x8 ahi = __builtin_bit_cast(s16x8, vh);                                   \
    s16x8 alo = __builtin_bit_cast(s16x8, vl);                                   \
    u32 ob = (u32)ks * 2048 + lfrag;                                             \
    s16x8 bh0 = *(const s16x8*)(base_hi + ob);                                   \
    s16x8 bl0 = *(const s16x8*)(base_lo + ob);                                   \
    s16x8 bh1 = *(const s16x8*)(base_hi + ob + 1024);                            \
    s16x8 bl1 = *(const s16x8*)(base_lo + ob + 1024);                            \
    acc0 = __builtin_amdgcn_mfma_f32_16x16x32_bf16(ahi, bh0, acc0, 0, 0, 0);     \
    acc1 = __builtin_amdgcn_mfma_f32_16x16x32_bf16(ahi, bh1, acc1, 0, 0, 0);     \
    acc0 = __builtin_amdgcn_mfma_f32_16x16x32_bf16(alo, bh0, acc0, 0, 0, 0);     \
    acc1 = __builtin_amdgcn_mfma_f32_16x16x32_bf16(alo, bh1, acc1, 0, 0, 0);     \
    acc0 = __builtin_amdgcn_mfma_f32_16x16x32_bf16(ahi, bl0, acc0, 0, 0, 0);     \
    acc1 = __builtin_amdgcn_mfma_f32_16x16x32_bf16(ahi, bl1, acc1, 0, 0, 0);     \
  }

  for (int t = 0; t < Tn; ++t) {
    f32x4 acc0 = {bias0, bias0, bias0, bias0};
    f32x4 acc1 = {bias1, bias1, bias1, bias1};

    // ---- x-projection FIRST (h-independent; W + inp both conflict-free) ----
    const unsigned short* ipA =
        inp2 + ((size_t)(t * 8 + (group * 4 + wv)) * 10) * 512 + l * 8;
#pragma unroll
    for (int ks = 0; ks < 10; ++ks) {
      s16x8 a = *(const s16x8*)(ipA + ks * 512);
      u32 ob = (u32)ks * 2048 + lfrag;
      s16x8 b0 = *(const s16x8*)(base_ih + ob);
      s16x8 b1 = *(const s16x8*)(base_ih + ob + 1024);
      acc0 = __builtin_amdgcn_mfma_f32_16x16x32_bf16(a, b0, acc0, 0, 0, 0);
      acc1 = __builtin_amdgcn_mfma_f32_16x16x32_bf16(a, b1, acc1, 0, 0, 0);
    }

    // ---- release: wave 0 polls the 128 flags; waves 1-3 sleep at the barrier ----
    if (t) {
      if (wv == 0) {
        u32 spins = 0;
        for (;;) {
          u32 f0 = LDQ32(fg + l);
          u32 f1 = LDQ32(fg + 64 + l);
          if (__ballot((f0 >= (u32)t) & (f1 >= (u32)t)) == ~0ull) break;
          __builtin_amdgcn_s_sleep(1);
          if (++spins > 400000u) break;  // watchdog: dead unless deadlock
        }
      }
      __syncthreads();
    }
    WAITV0;  // clean vmcnt before counted prefetch chain

    // ---- recurrent K=1024: 8 chunks, STAGGERED order (cb&7)+i, 4-deep counted
    //      vmcnt prefetch. All chunks are ready post-barrier; permutation only. ----
    const u32* hbase = h_pk + (size_t)(t & (NROT - 1)) * (Bn * Hn) +
                       (u32)(lq * 1024 + (b0w + lr) * 8);
    const int c0 = st, c1 = (st + 1) & 7, c2 = (st + 2) & 7, c3 = (st + 3) & 7;
    const int c4 = (st + 4) & 7, c5 = (st + 5) & 7, c6 = (st + 6) & 7, c7 = (st + 7) & 7;
    ISSUE_A(0, c0) ISSUE_A(1, c1) ISSUE_A(2, c2) ISSUE_A(3, c3)
    WAITV24; BODY_(0, c0) ISSUE_A(0, c4)
    WAITV24; BODY_(1, c1) ISSUE_A(1, c5)
    WAITV24; BODY_(2, c2) ISSUE_A(2, c6)
    WAITV24; BODY_(3, c3) ISSUE_A(3, c7)
    WAITV24; BODY_(0, c4)
    WAITV16; BODY_(1, c5)
    WAITV8;  BODY_(2, c6)
    WAITV0;  BODY_(3, c7)

    // ---- gates + state update; per-lane ST32 into block-major slice ----
    u32* const hout = h_pk + (size_t)((t + 1) & (NROT - 1)) * (Bn * Hn);
#pragma unroll
    for (int r = 0; r < 4; ++r) {
      float h0 = gate_update(acc0[r], creg0[r], gate);
      float h1 = gate_update(acc1[r], creg1[r], gate);
      unsigned short h0h = f2bf(h0);
      unsigned short h0l = f2bf(h0 - bf2f(h0h));
      unsigned short h1h = f2bf(h1);
      unsigned short h1l = f2bf(h1 - bf2f(h1h));
      if (gate == 0) {
        int b = b0w + lq * 4 + r;
        u32* slice = hout + (u32)(cb * 1024 + b * 8);
        ST32(slice + usub, (u32)h0h | ((u32)h0l << 16));
        ST32(slice + usub + 4, (u32)h1h | ((u32)h1l << 16));
        if (t == tsr[r]) {
          hsel[(size_t)b * Hn + u0 + usub] = pfr[r] ? 0.f : h0;
          hsel[(size_t)b * Hn + u0 + usub + 4] = pfr[r] ? 0.f : h1;
        }
      }
    }

    // ---- arrival: barrier (compiler drains each wave's vmcnt), publish flag ----
    __syncthreads();
    if (tid == 0) ST32(fg + cb, (u32)(t + 1));
    // every 8 steps: invalidate local L2/L1 h copies (weights are LDS-immune);
    // guarantees no stale h line survives to the address's reuse at t+16
    if ((t & 7) == 7) __builtin_amdgcn_fence(__ATOMIC_ACQUIRE, "agent");
  }
#undef ISSUE_A
#undef BODY_
}

// ---------------- K3: out[b][o] = hsel[b]·W_out[o] + b_out[o] ----------------
__global__ void head_kernel(const float* __restrict__ hsel, const float* __restrict__ Wout,
                            const float* __restrict__ bout, float* __restrict__ out) {
  int b = blockIdx.x;
  int l = threadIdx.x;  // 64 threads
  float s0 = 0.f, s1 = 0.f, s2 = 0.f;
  for (int j = l; j < Hn; j += 64) {
    float h = hsel[(size_t)b * Hn + j];
    s0 += h * Wout[j];
    s1 += h * Wout[Hn + j];
    s2 += h * Wout[2 * Hn + j];
  }
#pragma unroll
  for (int m = 32; m; m >>= 1) {
    s0 += __shfl_xor(s0, m);
    s1 += __shfl_xor(s1, m);
    s2 += __shfl_xor(s2, m);
  }
  if (l == 0) {
    out[b * 3 + 0] = s0 + bout[0];
    out[b * 3 + 1] = s1 + bout[1];
    out[b * 3 + 2] = s2 + bout[2];
  }
}

extern "C" void kernel_launch(void* const* d_in, const int* in_sizes, int n_in,
                              void* d_out, int out_size, void* d_ws, size_t ws_size,
                              hipStream_t stream) {
  const int* x = (const int*)d_in[0];
  const float* embed = (const float*)d_in[1];
  const float* Wih = (const float*)d_in[2];
  const float* Whh = (const float*)d_in[3];
  const float* bih = (const float*)d_in[4];
  const float* bhh = (const float*)d_in[5];
  const float* Wout = (const float*)d_in[6];
  const float* bout = (const float*)d_in[7];
  float* out = (float*)d_out;

  // ws layout
  const size_t INP2_BYTES = (size_t)Tn * 8 * 10 * 512 * 2;   // 20,971,520
  const size_t HPK_BYTES = (size_t)NROT * Bn * Hn * 4;       //  8,388,608
  const size_t HSEL_BYTES = (size_t)Bn * Hn * 4;             //    524,288
  char* p = (char*)d_ws;
  unsigned short* inp2 = (unsigned short*)p;            p += INP2_BYTES;
  u32* h_pk = (u32*)p;                                  p += HPK_BYTES;
  float* hsel = (float*)p;                              p += HSEL_BYTES;
  int* tstar = (int*)p;                                 p += 512;
  int* padflag = (int*)p;                               p += 512;
  u32* flags = (u32*)p;                                 p += 1024;

  // per-launch init: h(0) = 0 (rotation slot 0), flags = 0 (self-contained replay)
  hipMemsetAsync(h_pk, 0, (size_t)Bn * Hn * 4, stream);
  hipMemsetAsync(flags, 0, 1024, stream);

  prep_kernel<<<1, 128, 0, stream>>>(x, tstar, padflag);
  gather2_kernel<<<40960, 256, 0, stream>>>(x, embed, inp2);
  lstm_scan<<<NBLK, 256, 0, stream>>>(Whh, Wih, bih, bhh, inp2, tstar, padflag,
                                      h_pk, hsel, flags);
  head_kernel<<<Bn, 64, 0, stream>>>(hsel, Wout, bout, out);
}

// Round 13
// 2025.502 us; speedup vs baseline: 1.8252x; 1.0508x over previous
//
#include <hip/hip_runtime.h>
#include <stdint.h>

#define Bn 128
#define Tn 256
#define En 300
#define Hn 1024
#define PADIDX 1
#define NBLK 256         // 2 groups x 128 col-blocks
#define NROT 16          // h buffer rotation depth (fresh address per step)

typedef short s16x8 __attribute__((ext_vector_type(8)));
typedef float f32x4 __attribute__((ext_vector_type(4)));
typedef unsigned int u32;
typedef u32 u32x4 __attribute__((ext_vector_type(4)));

#define LDQ32(p) __hip_atomic_load((p), __ATOMIC_RELAXED, __HIP_MEMORY_SCOPE_SYSTEM)
#define ST32(p, v) __hip_atomic_store((p), (v), __ATOMIC_RELAXED, __HIP_MEMORY_SCOPE_SYSTEM)

__device__ __forceinline__ unsigned short f2bf(float f) {
  u32 u = __builtin_bit_cast(u32, f);
  u32 r = (u + 0x7fffu + ((u >> 16) & 1u)) >> 16;  // RNE
  return (unsigned short)r;
}
__device__ __forceinline__ float bf2f(unsigned short h) {
  u32 u = ((u32)h) << 16;
  return __builtin_bit_cast(float, u);
}
__device__ __forceinline__ float sigmoidf_(float x) { return 1.f / (1.f + __expf(-x)); }
__device__ __forceinline__ float tanhf_(float x) { return 1.f - 2.f / (__expf(2.f * x) + 1.f); }

// h load: sc0 only -> bypass L1, cache in XCD L2 (co-XCD amortization). Result
// NOT valid until manual s_waitcnt.
__device__ __forceinline__ u32x4 ldg_sc0_x4(const u32* p) {
  u32x4 r;
  asm volatile("global_load_dwordx4 %0, %1, off sc0" : "=v"(r) : "v"(p));
  return r;
}
#define WAITV24 do { asm volatile("s_waitcnt vmcnt(24)" ::: "memory"); \
                     __builtin_amdgcn_sched_barrier(0); } while (0)
#define WAITV16 do { asm volatile("s_waitcnt vmcnt(16)" ::: "memory"); \
                     __builtin_amdgcn_sched_barrier(0); } while (0)
#define WAITV8  do { asm volatile("s_waitcnt vmcnt(8)" ::: "memory");  \
                     __builtin_amdgcn_sched_barrier(0); } while (0)
#define WAITV0  do { asm volatile("s_waitcnt vmcnt(0)" ::: "memory");  \
                     __builtin_amdgcn_sched_barrier(0); } while (0)

// lane holds gate `gate` value v for its (b,unit); recover all 4 gates via shfl
__device__ __forceinline__ float gate_update(float pre, float& c, int gate) {
  float v = (gate == 2) ? tanhf_(pre) : sigmoidf_(pre);
  float vB = __shfl_xor(v, 4);
  float vC = __shfl_xor(v, 8);
  float vD = __shfl_xor(vB, 8);
  float i_ = (gate & 2) ? ((gate & 1) ? vD : vC) : ((gate & 1) ? vB : v);
  float f_ = (gate & 2) ? ((gate & 1) ? vC : vD) : ((gate & 1) ? v : vB);
  float g_ = (gate & 2) ? ((gate & 1) ? vB : v) : ((gate & 1) ? vD : vC);
  float o_ = (gate & 2) ? ((gate & 1) ? v : vB) : ((gate & 1) ? vC : vD);
  float cn = f_ * c + i_ * g_;
  c = cn;
  return o_ * tanhf_(cn);
}

// ---------------- K0: lengths -> tstar / padflag ----------------
__global__ void prep_kernel(const int* __restrict__ x, int* __restrict__ tstar,
                            int* __restrict__ padflag) {
  int b = threadIdx.x;
  if (b < Bn) {
    int len = 0;
    for (int t = 0; t < Tn; ++t) len += (x[b * Tn + t] != PADIDX) ? 1 : 0;
    int ts = (len > 0) ? (len - 1) : (Tn - 1);  // jax wraps index -1
    tstar[b] = ts;
    padflag[b] = (x[b * Tn + ts] == PADIDX) ? 1 : 0;
  }
}

// ---------------- K1: embedding gather, A-fragment-linear (R5/R10-verified) -----
// inp2[((t*8 + rg)*10 + ks)*64 + l][8] ; rg = group*4+wv ; b = rg*16+(l&15) ;
// k = ks*32 + (l>>4)*8 + jj ; zero-padded past 300.
__global__ void gather2_kernel(const int* __restrict__ x, const float* __restrict__ embed,
                               unsigned short* __restrict__ inp2) {
  int idx = blockIdx.x * 256 + threadIdx.x;  // total 256*8*10*512 = 10,485,760
  int jj = idx & 7;
  int tmp = idx >> 3;
  int l = tmp & 63; tmp >>= 6;
  int ks = tmp % 10; tmp /= 10;
  int rg = tmp & 7;
  int t = tmp >> 3;
  int b = rg * 16 + (l & 15);
  int k = ks * 32 + (l >> 4) * 8 + jj;
  int tok = x[b * Tn + t];
  float v = (k < En) ? embed[(size_t)tok * En + k] : 0.f;
  inp2[idx] = f2bf(v);
}

// ---------------- K2: persistent LSTM scan (single-bf16 h) ----------------
// 256 blocks x 256 thr (4 waves). group = bid>>7 (64 batches); 128 col-blocks/group,
// each 8 hidden units (32 gate cols). LDS: W_hh hi/lo (128 KB) + W_ih (20 KB) in
// 0-conflict fragment-linear layout. NEW: h carried as SINGLE bf16 (W stays hi/lo
// — only state quantized). Halves h broadcast (64->32 MB/step), removes all alo
// MFMA products (192->128/wave/step) and all v_perm unpacks; A-fragment IS the
// 16B load. h block-major [cb'][b][8 units] bf16; stores per-lane ST32 (bf16 pair
// packed via shfl_xor(1)) sc0sc1, loads sc0 (L2-fill). Rotation NROT=16 +
// acquire-fence every 8 steps kills stale lines before reuse. Sync = R10 barrier.
__global__ __launch_bounds__(256, 1) void lstm_scan(
    const float* __restrict__ Whh, const float* __restrict__ Wih,
    const float* __restrict__ bih, const float* __restrict__ bhh,
    const unsigned short* __restrict__ inp2, const int* __restrict__ tstar,
    const int* __restrict__ padflag, unsigned short* __restrict__ h_pk,
    float* __restrict__ hsel, u32* __restrict__ flags) {
  // elem index i = ks*1024 + ct*512 + lq*128 + lr*8 + j  (contig per (ks,ct) read)
  __shared__ unsigned short lds_hi[32768];   // 64 KB  W_hh hi
  __shared__ unsigned short lds_lo[32768];   // 64 KB  W_hh lo
  __shared__ unsigned short lds_ih[10240];   // 20 KB  W_ih (ks 0..9)

  const int bid = blockIdx.x;
  const int group = bid >> 7;              // 0: batches 0-63, 1: batches 64-127
  const int cb = bid & 127;                // col-block within group
  const int u0 = cb * 8;                   // 8 hidden units per block
  const int tid = threadIdx.x;

  // --- W_hh slice -> LDS hi/lo, fragment-linear ---
  for (int i = tid; i < 32768; i += 256) {
    int j = i & 7, lr = (i >> 3) & 15, lq = (i >> 7) & 3, ct = (i >> 9) & 1, ks = i >> 10;
    int col = (lr >> 2) * Hn + u0 + (lr & 3) + ct * 4;
    int k = ks * 32 + lq * 8 + j;
    float w = Whh[(size_t)col * Hn + k];
    unsigned short hi = f2bf(w);
    lds_hi[i] = hi;
    lds_lo[i] = f2bf(w - bf2f(hi));
  }
  // --- W_ih slice -> LDS, same fragment-linear layout, K padded to 320 ---
  for (int i = tid; i < 10240; i += 256) {
    int j = i & 7, lr = (i >> 3) & 15, lq = (i >> 7) & 3, ct = (i >> 9) & 1, ks = i >> 10;
    int col = (lr >> 2) * Hn + u0 + (lr & 3) + ct * 4;
    int k = ks * 32 + lq * 8 + j;
    float v = (k < En) ? Wih[(size_t)col * En + k] : 0.f;
    lds_ih[i] = f2bf(v);
  }
  __syncthreads();

  const int wv = tid >> 6, l = tid & 63;
  const int lr = l & 15;                    // A-row (batch) / D-col in tile
  const int lq = l >> 4;                    // quadrant
  const int usub = lr & 3, gate = lr >> 2;
  const int b0w = group * 64 + wv * 16;     // this wave's 16 batch rows
  const int col0 = gate * Hn + u0 + usub;   // ct=0 gate column; ct=1 is col0+4
  const float bias0 = bih[col0] + bhh[col0];
  const float bias1 = bih[col0 + 4] + bhh[col0 + 4];
  const u32 lfrag = (u32)(lq * 256 + lr * 16);   // per-lane byte in 1 KB fragment
  const int st = cb & 7;                    // stagger: chunk start offset
  u32* const fg = flags + (group << 7);     // group's 128 per-block flags

  int tsr[4], pfr[4];
#pragma unroll
  for (int r = 0; r < 4; ++r) {
    int b = b0w + lq * 4 + r;
    tsr[r] = tstar[b];
    pfr[r] = padflag[b];
  }
  float creg0[4] = {0.f, 0.f, 0.f, 0.f};
  float creg1[4] = {0.f, 0.f, 0.f, 0.f};

  const char* base_hi = (const char*)lds_hi;
  const char* base_lo = (const char*)lds_lo;
  const char* base_ih = (const char*)lds_ih;

  u32x4 qa[8][4];  // h prefetch: 8 chunk buffers x 4 ks x 16B (single bf16)

// block-major addressing (shorts): addr = (4*ks + lq)*1024 + b*8 + j
// hbase = slot + lq*1024 + b*8 ; chunk/ks adds ks*4096
#define ISSUE_A(BUF, C)                                                          \
  _Pragma("unroll") for (int ii = 0; ii < 4; ++ii) {                             \
    qa[BUF][ii] = ldg_sc0_x4((const u32*)(hbase + ((C) * 4 + ii) * 4096));       \
  }
#define BODY_(BUF, C)                                                            \
  _Pragma("unroll") for (int ii = 0; ii < 4; ++ii) {                             \
    int ks = (C) * 4 + ii;                                                       \
    s16x8 ahi = __builtin_bit_cast(s16x8, qa[BUF][ii]);                          \
    u32 ob = (u32)ks * 2048 + lfrag;                                             \
    s16x8 bh0 = *(const s16x8*)(base_hi + ob);                                   \
    s16x8 bl0 = *(const s16x8*)(base_lo + ob);                                   \
    s16x8 bh1 = *(const s16x8*)(base_hi + ob + 1024);                            \
    s16x8 bl1 = *(const s16x8*)(base_lo + ob + 1024);                            \
    acc0 = __builtin_amdgcn_mfma_f32_16x16x32_bf16(ahi, bh0, acc0, 0, 0, 0);     \
    acc1 = __builtin_amdgcn_mfma_f32_16x16x32_bf16(ahi, bh1, acc1, 0, 0, 0);     \
    acc0 = __builtin_amdgcn_mfma_f32_16x16x32_bf16(ahi, bl0, acc0, 0, 0, 0);     \
    acc1 = __builtin_amdgcn_mfma_f32_16x16x32_bf16(ahi, bl1, acc1, 0, 0, 0);     \
  }

  for (int t = 0; t < Tn; ++t) {
    f32x4 acc0 = {bias0, bias0, bias0, bias0};
    f32x4 acc1 = {bias1, bias1, bias1, bias1};

    // ---- x-projection FIRST (h-independent; W + inp both conflict-free) ----
    const unsigned short* ipA =
        inp2 + ((size_t)(t * 8 + (group * 4 + wv)) * 10) * 512 + l * 8;
#pragma unroll
    for (int ks = 0; ks < 10; ++ks) {
      s16x8 a = *(const s16x8*)(ipA + ks * 512);
      u32 ob = (u32)ks * 2048 + lfrag;
      s16x8 b0 = *(const s16x8*)(base_ih + ob);
      s16x8 b1 = *(const s16x8*)(base_ih + ob + 1024);
      acc0 = __builtin_amdgcn_mfma_f32_16x16x32_bf16(a, b0, acc0, 0, 0, 0);
      acc1 = __builtin_amdgcn_mfma_f32_16x16x32_bf16(a, b1, acc1, 0, 0, 0);
    }

    // ---- release: wave 0 polls the 128 flags; waves 1-3 sleep at the barrier ----
    if (t) {
      if (wv == 0) {
        u32 spins = 0;
        for (;;) {
          u32 f0 = LDQ32(fg + l);
          u32 f1 = LDQ32(fg + 64 + l);
          if (__ballot((f0 >= (u32)t) & (f1 >= (u32)t)) == ~0ull) break;
          __builtin_amdgcn_s_sleep(1);
          if (++spins > 400000u) break;  // watchdog: dead unless deadlock
        }
      }
      __syncthreads();
    }
    WAITV0;  // clean vmcnt before counted prefetch chain

    // ---- recurrent K=1024: all 8 chunks issued upfront (32 loads in flight),
    //      staggered order (cb&7)+i, 4 counted waits ----
    const unsigned short* hbase = h_pk + (size_t)(t & (NROT - 1)) * (Bn * Hn) +
                                  (u32)(lq * 1024 + (b0w + lr) * 8);
    const int c0 = st, c1 = (st + 1) & 7, c2 = (st + 2) & 7, c3 = (st + 3) & 7;
    const int c4 = (st + 4) & 7, c5 = (st + 5) & 7, c6 = (st + 6) & 7, c7 = (st + 7) & 7;
    ISSUE_A(0, c0) ISSUE_A(1, c1) ISSUE_A(2, c2) ISSUE_A(3, c3)
    ISSUE_A(4, c4) ISSUE_A(5, c5) ISSUE_A(6, c6) ISSUE_A(7, c7)
    WAITV24; BODY_(0, c0) BODY_(1, c1)
    WAITV16; BODY_(2, c2) BODY_(3, c3)
    WAITV8;  BODY_(4, c4) BODY_(5, c5)
    WAITV0;  BODY_(6, c6) BODY_(7, c7)

    // ---- gates + state update; bf16 h, pair-packed ST32 (even usub lanes) ----
    unsigned short* const hout =
        h_pk + (size_t)((t + 1) & (NROT - 1)) * (Bn * Hn);
#pragma unroll
    for (int r = 0; r < 4; ++r) {
      float h0 = gate_update(acc0[r], creg0[r], gate);
      float h1 = gate_update(acc1[r], creg1[r], gate);
      u32 h0h = (u32)f2bf(h0);
      u32 h1h = (u32)f2bf(h1);
      u32 n0 = (u32)__shfl_xor((int)h0h, 1);   // neighbor usub^1 (convergent)
      u32 n1 = (u32)__shfl_xor((int)h1h, 1);
      if (gate == 0) {
        int b = b0w + lq * 4 + r;
        if ((usub & 1) == 0) {
          unsigned short* slice = hout + (u32)(cb * 1024 + b * 8);
          ST32((u32*)(slice + usub), h0h | (n0 << 16));
          ST32((u32*)(slice + usub + 4), h1h | (n1 << 16));
        }
        if (t == tsr[r]) {
          hsel[(size_t)b * Hn + u0 + usub] = pfr[r] ? 0.f : h0;
          hsel[(size_t)b * Hn + u0 + usub + 4] = pfr[r] ? 0.f : h1;
        }
      }
    }

    // ---- arrival: barrier (compiler drains each wave's vmcnt), publish flag ----
    __syncthreads();
    if (tid == 0) ST32(fg + cb, (u32)(t + 1));
    // every 8 steps: invalidate local L2/L1 h copies (weights are LDS-immune);
    // guarantees no stale h line survives to the address's reuse at t+16
    if ((t & 7) == 7) __builtin_amdgcn_fence(__ATOMIC_ACQUIRE, "agent");
  }
#undef ISSUE_A
#undef BODY_
}

// ---------------- K3: out[b][o] = hsel[b]·W_out[o] + b_out[o] ----------------
__global__ void head_kernel(const float* __restrict__ hsel, const float* __restrict__ Wout,
                            const float* __restrict__ bout, float* __restrict__ out) {
  int b = blockIdx.x;
  int l = threadIdx.x;  // 64 threads
  float s0 = 0.f, s1 = 0.f, s2 = 0.f;
  for (int j = l; j < Hn; j += 64) {
    float h = hsel[(size_t)b * Hn + j];
    s0 += h * Wout[j];
    s1 += h * Wout[Hn + j];
    s2 += h * Wout[2 * Hn + j];
  }
#pragma unroll
  for (int m = 32; m; m >>= 1) {
    s0 += __shfl_xor(s0, m);
    s1 += __shfl_xor(s1, m);
    s2 += __shfl_xor(s2, m);
  }
  if (l == 0) {
    out[b * 3 + 0] = s0 + bout[0];
    out[b * 3 + 1] = s1 + bout[1];
    out[b * 3 + 2] = s2 + bout[2];
  }
}

extern "C" void kernel_launch(void* const* d_in, const int* in_sizes, int n_in,
                              void* d_out, int out_size, void* d_ws, size_t ws_size,
                              hipStream_t stream) {
  const int* x = (const int*)d_in[0];
  const float* embed = (const float*)d_in[1];
  const float* Wih = (const float*)d_in[2];
  const float* Whh = (const float*)d_in[3];
  const float* bih = (const float*)d_in[4];
  const float* bhh = (const float*)d_in[5];
  const float* Wout = (const float*)d_in[6];
  const float* bout = (const float*)d_in[7];
  float* out = (float*)d_out;

  // ws layout
  const size_t INP2_BYTES = (size_t)Tn * 8 * 10 * 512 * 2;   // 20,971,520
  const size_t HPK_BYTES = (size_t)NROT * Bn * Hn * 2;       //  4,194,304
  const size_t HSEL_BYTES = (size_t)Bn * Hn * 4;             //    524,288
  char* p = (char*)d_ws;
  unsigned short* inp2 = (unsigned short*)p;            p += INP2_BYTES;
  unsigned short* h_pk = (unsigned short*)p;            p += HPK_BYTES;
  float* hsel = (float*)p;                              p += HSEL_BYTES;
  int* tstar = (int*)p;                                 p += 512;
  int* padflag = (int*)p;                               p += 512;
  u32* flags = (u32*)p;                                 p += 1024;

  // per-launch init: h(0) = 0 (rotation slot 0), flags = 0 (self-contained replay)
  hipMemsetAsync(h_pk, 0, (size_t)Bn * Hn * 2, stream);
  hipMemsetAsync(flags, 0, 1024, stream);

  prep_kernel<<<1, 128, 0, stream>>>(x, tstar, padflag);
  gather2_kernel<<<40960, 256, 0, stream>>>(x, embed, inp2);
  lstm_scan<<<NBLK, 256, 0, stream>>>(Whh, Wih, bih, bhh, inp2, tstar, padflag,
                                      h_pk, hsel, flags);
  head_kernel<<<Bn, 64, 0, stream>>>(hsel, Wout, bout, out);
}